// Round 5
// baseline (394.780 us; speedup 1.0000x reference)
//
#include <hip/hip_runtime.h>
#include <hip/hip_bf16.h>

typedef __attribute__((ext_vector_type(16))) float f32x16;
typedef __attribute__((ext_vector_type(8))) short bf16x8;
typedef unsigned short u16;

#define SEQ 2048
#define HID 1024
#define NROWS 16384

// ---------- helpers ----------
__device__ __forceinline__ float b2f(u16 u) {
    union { float f; unsigned i; } x; x.i = ((unsigned)u) << 16; return x.f;
}
__device__ __forceinline__ u16 f2b(float f) {
    unsigned x = __float_as_uint(f);
    return (u16)((x + 0x7fffu + ((x >> 16) & 1u)) >> 16);
}
__device__ __forceinline__ void gload16(const u16* g, u16* l) {
    __builtin_amdgcn_global_load_lds(
        (const __attribute__((address_space(1))) void*)g,
        (__attribute__((address_space(3))) void*)l,
        16, 0, 0);
}

// ---------- fp32 -> bf16 convert (with scale) ----------
__global__ __launch_bounds__(256)
void cvt_kernel(const float* __restrict__ src, u16* __restrict__ dst, int n, float scale) {
    int base = (blockIdx.x * 256 + threadIdx.x) * 4;
    if (base < n) {
        float4 v = *(const float4*)&src[base];
        ushort4 o;
        o.x = f2b(v.x * scale); o.y = f2b(v.y * scale);
        o.z = f2b(v.z * scale); o.w = f2b(v.w * scale);
        *(ushort4*)&dst[base] = o;
    }
}

// ---------- GEMM: C = A @ B^T (+bias) (+resid) ----------
// 256x256 tile, BK=64, 512 thr (8 waves 2Mx4N), per-wave 128x64 out.
// mfma_f32_32x32x16_bf16; per-wave acc = 4x2 tiles of 32x32 (f32x16).
// 8-phase schedule (T3+T4+T5), counted vmcnt(2) at ends of P1/P4 only.
// LDS XOR swizzle (T2, rule 21): linear gload_lds dest + inv-swizzled source.
// OUTMODE 0: bf16 write (ldc), batch bz*sC, bias=bq (may be null)
// OUTMODE 2: fp32 write + bias(bq) + resid
// OUTMODE 3: fused QKV: n0<2048 -> bf16 write into C (qkb, ldc=2048) with
//            bias bq*(1/32 pre-scaled weights? no: bq scaled here)/bk;
//            n0>=2048 -> transposed write into vT[b][h][s] with bias bv.
template<int OUTMODE>
__global__ __launch_bounds__(512, 2)
void gemm_kernel(const u16* __restrict__ A, const u16* __restrict__ B,
                 void* __restrict__ C, u16* __restrict__ vT,
                 const float* __restrict__ bq, const float* __restrict__ bk,
                 const float* __restrict__ bvp, const float* __restrict__ resid,
                 int K, int lda, int ldb,
                 long long sA, long long sB, long long sC, int ldc)
{
    // ---- XCD-bijective block swizzle (T1); all grids have nwg % 8 == 0.
    const unsigned nwg = gridDim.x * gridDim.y * gridDim.z;
    const unsigned bid = blockIdx.x + gridDim.x * (blockIdx.y + gridDim.y * blockIdx.z);
    const unsigned work = (bid & 7u) * (nwg >> 3) + (bid >> 3);
    const unsigned bx = work % gridDim.x;
    const unsigned rem = work / gridDim.x;
    const unsigned by = rem % gridDim.y;
    const unsigned bz = rem / gridDim.y;

    A += (long long)bz * sA;
    B += (long long)bz * sB;

    const int tid  = threadIdx.x;
    const int lane = tid & 63;
    const int w    = tid >> 6;
    const int wm   = w >> 2;      // 0..1
    const int wn   = w & 3;       // 0..3
    const int l31  = lane & 31;
    const int hi   = lane >> 5;   // 0..1
    const int hi8  = hi << 3;

    const int m0 = by * 256;
    const int n0 = bx * 256;

    __shared__ u16 lds[65536];    // 2 buffers x (A 256x64 + B 256x64)

    f32x16 acc[4][2] = {};
    bf16x8 aF[2][2], bF[2][2];

    const int sr  = tid >> 3;              // 0..63
    const int sc8 = (tid & 7) << 3;        // u16 chunk col
    const int scb = sc8 ^ ((sr & 7) << 3); // inverse-swizzled global col

    const int nk = K >> 6;

#define STAGE_A(tt, q01, bsel) { \
    const int kb_ = (tt) << 6; \
    u16* dst_ = &lds[(bsel) * 32768]; \
    { const int row_ = (q01) * 64 + sr; \
      gload16(A + (size_t)(m0 + row_) * lda + kb_ + scb, &dst_[row_ * 64 + sc8]); } \
    { const int row_ = ((q01) + 2) * 64 + sr; \
      gload16(A + (size_t)(m0 + row_) * lda + kb_ + scb, &dst_[row_ * 64 + sc8]); } }

#define STAGE_B(tt, h, bsel) { \
    const int kb_ = (tt) << 6; \
    u16* dst_ = &lds[(bsel) * 32768 + 16384]; \
    { const int row_ = (h) * 128 + sr; \
      gload16(B + (size_t)(n0 + row_) * ldb + kb_ + scb, &dst_[row_ * 64 + sc8]); } \
    { const int row_ = (h) * 128 + 64 + sr; \
      gload16(B + (size_t)(n0 + row_) * ldb + kb_ + scb, &dst_[row_ * 64 + sc8]); } }

#define READ_A32(mh, kp) { \
    _Pragma("unroll") for (int mi_ = 0; mi_ < 2; ++mi_) \
    _Pragma("unroll") for (int ks_ = 0; ks_ < 2; ++ks_) { \
      const int r_ = wm * 128 + ((mh) * 2 + mi_) * 32 + l31; \
      const int c_ = ((((kp) * 2 + ks_) * 16 + hi8) ^ ((r_ & 7) << 3)); \
      aF[mi_][ks_] = *(const bf16x8*)&Alp[r_ * 64 + c_]; } }

#define READ_B32(kp) { \
    _Pragma("unroll") for (int ni_ = 0; ni_ < 2; ++ni_) \
    _Pragma("unroll") for (int ks_ = 0; ks_ < 2; ++ks_) { \
      const int r_ = wn * 64 + ni_ * 32 + l31; \
      const int c_ = ((((kp) * 2 + ks_) * 16 + hi8) ^ ((r_ & 7) << 3)); \
      bF[ni_][ks_] = *(const bf16x8*)&Blp[r_ * 64 + c_]; } }

#define MFMA_PH(mh) \
    _Pragma("unroll") for (int ks_ = 0; ks_ < 2; ++ks_) \
    _Pragma("unroll") for (int mi_ = 0; mi_ < 2; ++mi_) \
    _Pragma("unroll") for (int ni_ = 0; ni_ < 2; ++ni_) \
      acc[(mh) * 2 + mi_][ni_] = __builtin_amdgcn_mfma_f32_32x32x16_bf16(aF[mi_][ks_], bF[ni_][ks_], acc[(mh) * 2 + mi_][ni_], 0, 0, 0);

#define BAR()   __builtin_amdgcn_s_barrier()
#define LGKM0() { asm volatile("s_waitcnt lgkmcnt(0)" ::: "memory"); __builtin_amdgcn_sched_barrier(0); }
#define VM(n)   asm volatile("s_waitcnt vmcnt(" #n ")" ::: "memory")
#define PRIO1() __builtin_amdgcn_s_setprio(1)
#define PRIO0() __builtin_amdgcn_s_setprio(0)

    // prologue: tile 0, halves in issue order A0,B0,B1,A1
    STAGE_A(0, 0, 0); STAGE_B(0, 0, 0); STAGE_B(0, 1, 0); STAGE_A(0, 1, 0);
    VM(2); BAR();

    for (int t = 0; t < nk - 1; ++t) {
        const u16* Alp = &lds[(t & 1) * 32768];
        const u16* Blp = Alp + 16384;
        const int nb = (t + 1) & 1;
        // P1: mh0 ksp0
        STAGE_A(t + 1, 0, nb);
        READ_B32(0); READ_A32(0, 0);
        BAR(); LGKM0();
        PRIO1(); MFMA_PH(0); PRIO0();
        VM(2); BAR();
        // P2: mh1 ksp0 (reuses bF)
        STAGE_B(t + 1, 0, nb);
        READ_A32(1, 0);
        BAR(); LGKM0();
        PRIO1(); MFMA_PH(1); PRIO0();
        BAR();
        // P3: mh0 ksp1
        STAGE_B(t + 1, 1, nb);
        READ_B32(1); READ_A32(0, 1);
        BAR(); LGKM0();
        PRIO1(); MFMA_PH(0); PRIO0();
        BAR();
        // P4: mh1 ksp1
        STAGE_A(t + 1, 1, nb);
        READ_A32(1, 1);
        BAR(); LGKM0();
        PRIO1(); MFMA_PH(1); PRIO0();
        VM(2); BAR();
    }
    {   // peeled last tile (no staging)
        const u16* Alp = &lds[((nk - 1) & 1) * 32768];
        const u16* Blp = Alp + 16384;
        READ_B32(0); READ_A32(0, 0);
        BAR(); LGKM0();
        PRIO1(); MFMA_PH(0); PRIO0();
        VM(0); BAR();
        READ_A32(1, 0);
        BAR(); LGKM0();
        PRIO1(); MFMA_PH(1); PRIO0();
        BAR();
        READ_B32(1); READ_A32(0, 1);
        BAR(); LGKM0();
        PRIO1(); MFMA_PH(0); PRIO0();
        BAR();
        READ_A32(1, 1);
        BAR(); LGKM0();
        PRIO1(); MFMA_PH(1); PRIO0();
        BAR();   // gates LDS reuse by epilogue
    }

    // ---- epilogues (32x32 C/D: col=lane&31, row=(reg&3)+8*(reg>>2)+4*hi) ----
    const int rg4 = lane >> 4;    // 0..3
    const int c16 = lane & 15;

    const bool qk_path = (OUTMODE != 3) || (n0 < 2048);

    if (qk_path) {
        // bf16/f32 row-major output via per-wave LDS f32 transpose [32][68]
        float* ep = (float*)lds + w * 2176;
        float4 b4 = make_float4(0.f, 0.f, 0.f, 0.f);
        int ldc_ = ldc;
        const float* bsrc = bq;
        float bsc = 1.0f;
        if constexpr (OUTMODE == 3) {
            if (n0 < 1024) { bsrc = bq + n0; bsc = 0.03125f; }
            else           { bsrc = bk + (n0 - 1024); }
            ldc_ = 2048;
        }
        if constexpr (OUTMODE == 3) {
            float4 t = *(const float4*)&bsrc[wn * 64 + c16 * 4];
            b4.x = t.x * bsc; b4.y = t.y * bsc; b4.z = t.z * bsc; b4.w = t.w * bsc;
        } else if (bq) {
            b4 = *(const float4*)&bq[n0 + wn * 64 + c16 * 4];
        }
#pragma unroll
        for (int mi = 0; mi < 4; ++mi) {
#pragma unroll
            for (int ni = 0; ni < 2; ++ni)
#pragma unroll
                for (int reg = 0; reg < 16; ++reg) {
                    const int row = (reg & 3) + 8 * (reg >> 2) + 4 * hi;
                    ep[row * 68 + ni * 32 + l31] = acc[mi][ni][reg];
                }
            LGKM0();
#pragma unroll
            for (int j = 0; j < 8; ++j) {
                const int row = j * 4 + rg4;
                float4 v = *(const float4*)&ep[row * 68 + c16 * 4];
                const int gr = m0 + wm * 128 + mi * 32 + row;
                const int gc = (OUTMODE == 3 ? n0 : n0) + wn * 64 + c16 * 4;
                if constexpr (OUTMODE == 2) {
                    float* Cf = (float*)C;
                    size_t o = (size_t)gr * ldc + gc;
                    float4 rv = *(const float4*)&resid[o];
                    float4 ov;
                    ov.x = v.x + b4.x + rv.x;
                    ov.y = v.y + b4.y + rv.y;
                    ov.z = v.z + b4.z + rv.z;
                    ov.w = v.w + b4.w + rv.w;
                    *(float4*)&Cf[o] = ov;
                } else {
                    u16* Cb = (u16*)C + (long long)bz * sC;
                    ushort4 pk;
                    pk.x = f2b(v.x + b4.x);
                    pk.y = f2b(v.y + b4.y);
                    pk.z = f2b(v.z + b4.z);
                    pk.w = f2b(v.w + b4.w);
                    *(ushort4*)&Cb[(size_t)gr * (OUTMODE == 3 ? ldc_ : ldc) + gc] = pk;
                }
            }
            LGKM0();
        }
    } else {
        // OUTMODE 3, v path: vT[b][h][s], per-wave LDS [64 h][128 s] u16 swizzled
        u16* epW = &lds[w * 8192];
        const int colv = (n0 - 2048) + wn * 64;
        float bvv[2];
#pragma unroll
        for (int ni = 0; ni < 2; ++ni) bvv[ni] = bvp[colv + ni * 32 + l31];
#pragma unroll
        for (int mi = 0; mi < 4; ++mi)
#pragma unroll
            for (int ni = 0; ni < 2; ++ni) {
                const int cl = ni * 32 + l31;
                const int swc = (cl & 7) << 3;
#pragma unroll
                for (int p = 0; p < 8; ++p) {
                    const int s0 = mi * 32 + 8 * (p >> 1) + 4 * hi + (p & 1) * 2;
                    unsigned lo = f2b(acc[mi][ni][2 * p]     + bvv[ni]);
                    unsigned hi_ = f2b(acc[mi][ni][2 * p + 1] + bvv[ni]);
                    *(unsigned*)&epW[cl * 128 + (s0 ^ swc)] = lo | (hi_ << 16);
                }
            }
        LGKM0();
        const int b  = (m0 + wm * 128) >> 11;
        const int sb = (m0 + wm * 128) & 2047;
#pragma unroll
        for (int j = 0; j < 16; ++j) {
            const int cl = j * 4 + rg4;
            const int sc_ = (c16 * 8) ^ ((cl & 7) << 3);
            bf16x8 v = *(const bf16x8*)&epW[cl * 128 + sc_];
            *(bf16x8*)&vT[((size_t)b * HID + colv + cl) * SEQ + sb + c16 * 8] = v;
        }
    }
#undef STAGE_A
#undef STAGE_B
#undef READ_A32
#undef READ_B32
#undef MFMA_PH
#undef BAR
#undef LGKM0
#undef VM
#undef PRIO1
#undef PRIO0
}

// ---------- row softmax, in-place, bf16, row length 2048 ----------
__global__ __launch_bounds__(256)
void softmax_kernel(u16* __restrict__ sc) {
    const size_t row = blockIdx.x;
    u16* p = sc + row * 2048;
    const int tid = threadIdx.x;
    const int lane = tid & 63;
    const int w = tid >> 6;

    float v[8];
    ushort4 ua = *(const ushort4*)&p[tid * 8];
    ushort4 ub = *(const ushort4*)&p[tid * 8 + 4];
    v[0] = b2f(ua.x); v[1] = b2f(ua.y); v[2] = b2f(ua.z); v[3] = b2f(ua.w);
    v[4] = b2f(ub.x); v[5] = b2f(ub.y); v[6] = b2f(ub.z); v[7] = b2f(ub.w);

    float mx = v[0];
#pragma unroll
    for (int j = 1; j < 8; ++j) mx = fmaxf(mx, v[j]);
#pragma unroll
    for (int o = 32; o; o >>= 1) mx = fmaxf(mx, __shfl_xor(mx, o));

    __shared__ float red[8];
    if (!lane) red[w] = mx;
    __syncthreads();
    mx = fmaxf(fmaxf(red[0], red[1]), fmaxf(red[2], red[3]));

    float s = 0.f;
#pragma unroll
    for (int j = 0; j < 8; ++j) { v[j] = __expf(v[j] - mx); s += v[j]; }
#pragma unroll
    for (int o = 32; o; o >>= 1) s += __shfl_xor(s, o);
    if (!lane) red[4 + w] = s;
    __syncthreads();
    s = red[4] + red[5] + red[6] + red[7];
    float inv = 1.0f / s;

    ushort4 oa, ob;
    oa.x = f2b(v[0] * inv); oa.y = f2b(v[1] * inv); oa.z = f2b(v[2] * inv); oa.w = f2b(v[3] * inv);
    ob.x = f2b(v[4] * inv); ob.y = f2b(v[5] * inv); ob.z = f2b(v[6] * inv); ob.w = f2b(v[7] * inv);
    *(ushort4*)&p[tid * 8]     = oa;
    *(ushort4*)&p[tid * 8 + 4] = ob;
}

// ---------- in-place LayerNorm over rows of 1024 fp32 ----------
__global__ __launch_bounds__(256)
void layernorm_kernel(float* __restrict__ y,
                      const float* __restrict__ gamma,
                      const float* __restrict__ beta) {
    const size_t row = blockIdx.x;
    float* p = y + row * 1024;
    const int tid = threadIdx.x;
    const int lane = tid & 63;
    const int w = tid >> 6;

    float4 v = *(const float4*)&p[tid * 4];
    float s = v.x + v.y + v.z + v.w;
    float q = v.x * v.x + v.y * v.y + v.z * v.z + v.w * v.w;
#pragma unroll
    for (int o = 32; o; o >>= 1) { s += __shfl_xor(s, o); q += __shfl_xor(q, o); }

    __shared__ float red[16];
    if (!lane) { red[w] = s; red[8 + w] = q; }
    __syncthreads();
    s = red[0] + red[1] + red[2] + red[3];
    q = red[8] + red[9] + red[10] + red[11];

    const float mu  = s * (1.0f / 1024.0f);
    const float var = q * (1.0f / 1024.0f) - mu * mu;
    const float rs  = rsqrtf(var + 1e-5f);

    float4 g  = *(const float4*)&gamma[tid * 4];
    float4 be = *(const float4*)&beta[tid * 4];
    float4 o;
    o.x = (v.x - mu) * rs * g.x + be.x;
    o.y = (v.y - mu) * rs * g.y + be.y;
    o.z = (v.z - mu) * rs * g.z + be.z;
    o.w = (v.w - mu) * rs * g.w + be.w;
    *(float4*)&p[tid * 4] = o;
}

extern "C" void kernel_launch(void* const* d_in, const int* in_sizes, int n_in,
                              void* d_out, int out_size, void* d_ws, size_t ws_size,
                              hipStream_t stream) {
    const float* x     = (const float*)d_in[0];
    const float* Wq    = (const float*)d_in[1];
    const float* bq    = (const float*)d_in[2];
    const float* Wk    = (const float*)d_in[3];
    const float* bk    = (const float*)d_in[4];
    const float* Wv    = (const float*)d_in[5];
    const float* bv    = (const float*)d_in[6];
    const float* Wp    = (const float*)d_in[7];
    const float* bp    = (const float*)d_in[8];
    const float* gamma = (const float*)d_in[9];
    const float* beta  = (const float*)d_in[10];
    float* out = (float*)d_out;

    char* ws = (char*)d_ws;
    u16* xb     = (u16*)(ws + 0);            // [16384][1024] 32 MB
    u16* qkb    = (u16*)(ws + 33554432);     // [16384][2048] 64 MB (q | k)
    u16* vT     = (u16*)(ws + 100663296);    // [8][1024][2048] 32 MB
    u16* ctx    = (u16*)(ws + 134217728);    // [16384][1024] 32 MB
    u16* wqb    = (u16*)(ws + 167772160);    // [1024][1024] (scaled 1/32)
    u16* wkb    = (u16*)(ws + 169869312);    // contiguous -> W_qkv [3072][1024]
    u16* wvb    = (u16*)(ws + 171966464);
    u16* wpb    = (u16*)(ws + 174063616);
    u16* scores = (u16*)(ws + 176160768);    // [8][2048][2048] 64 MB

    cvt_kernel<<<16384, 256, 0, stream>>>(x,  xb,  NROWS * HID, 1.0f);
    cvt_kernel<<<1024, 256, 0, stream>>>(Wq, wqb, HID * HID, 0.03125f);  // fold 1/sqrt(H)
    cvt_kernel<<<1024, 256, 0, stream>>>(Wk, wkb, HID * HID, 1.0f);
    cvt_kernel<<<1024, 256, 0, stream>>>(Wv, wvb, HID * HID, 1.0f);
    cvt_kernel<<<1024, 256, 0, stream>>>(Wp, wpb, HID * HID, 1.0f);

    dim3 blk(512);
    // fused QKV projection: [16384] x [3072] x K=1024
    gemm_kernel<3><<<dim3(12, 64, 1), blk, 0, stream>>>(
        xb, wqb, qkb, vT, bq, bk, bv, nullptr,
        HID, HID, HID, 0, 0, 0, 2048);

    // scores = q' @ k^T per batch (q = qkb cols 0-1023, k = cols 1024-2047)
    gemm_kernel<0><<<dim3(8, 8, 8), blk, 0, stream>>>(
        qkb, qkb + 1024, scores, nullptr, nullptr, nullptr, nullptr, nullptr,
        HID, 2048, 2048,
        (long long)SEQ * 2048, (long long)SEQ * 2048, (long long)SEQ * SEQ, SEQ);

    softmax_kernel<<<NROWS, 256, 0, stream>>>(scores);

    // context = attn @ v  (B = vT, K-contiguous)
    gemm_kernel<0><<<dim3(4, 8, 8), blk, 0, stream>>>(
        scores, vT, ctx, nullptr, nullptr, nullptr, nullptr, nullptr,
        SEQ, SEQ, SEQ,
        (long long)SEQ * SEQ, (long long)HID * SEQ, (long long)SEQ * HID, HID);

    // out = ctx @ Wp^T + bp + x  (fp32 into d_out)
    gemm_kernel<2><<<dim3(4, 64, 1), blk, 0, stream>>>(
        ctx, wpb, out, nullptr, bp, nullptr, nullptr, x,
        HID, HID, HID, 0, 0, 0, HID);

    layernorm_kernel<<<NROWS, 256, 0, stream>>>(out, gamma, beta);
}

// Round 6
// 370.231 us; speedup vs baseline: 1.0663x; 1.0663x over previous
//
#include <hip/hip_runtime.h>
#include <hip/hip_bf16.h>

typedef __attribute__((ext_vector_type(4))) float f32x4;
typedef __attribute__((ext_vector_type(8))) short bf16x8;
typedef unsigned short u16;

#define SEQ 2048
#define HID 1024
#define NROWS 16384

// ---------- helpers ----------
__device__ __forceinline__ float b2f(u16 u) {
    union { float f; unsigned i; } x; x.i = ((unsigned)u) << 16; return x.f;
}
__device__ __forceinline__ u16 f2b(float f) {
    unsigned x = __float_as_uint(f);
    return (u16)((x + 0x7fffu + ((x >> 16) & 1u)) >> 16);
}
__device__ __forceinline__ void gload16(const u16* g, u16* l) {
    __builtin_amdgcn_global_load_lds(
        (const __attribute__((address_space(1))) void*)g,
        (__attribute__((address_space(3))) void*)l,
        16, 0, 0);
}

// ---------- fp32 -> bf16 convert ----------
__global__ __launch_bounds__(256)
void cvt_kernel(const float* __restrict__ src, u16* __restrict__ dst, int n) {
    int base = (blockIdx.x * 256 + threadIdx.x) * 4;
    if (base < n) {
        float4 v = *(const float4*)&src[base];
        ushort4 o;
        o.x = f2b(v.x); o.y = f2b(v.y); o.z = f2b(v.z); o.w = f2b(v.w);
        *(ushort4*)&dst[base] = o;
    }
}

// ---------- GEMM: C = A @ B^T (+bias)*scale (+resid) ----------
// 256x256 tile, BK=64, 512 thr (8 waves 2Mx4N), per-wave 128x64 out,
// 16x16x32 MFMA (R4-proven conflict-free fragment reads).
// 8-phase schedule (T3+T4+T5) + NEW: one-phase-ahead ds_read pipelining with
// counted lgkmcnt(8/4) so LDS completion overlaps MFMA (m201's missing piece).
// Counted vmcnt(2) at ends of P1/P4 only (never 0 in main loop).
// LDS XOR swizzle (T2, rule 21): linear gload_lds dest + inv-swizzled source.
template<int OUTMODE>
__global__ __launch_bounds__(512, 2)
void gemm_bt_kernel(const u16* __restrict__ A, const u16* __restrict__ B,
                    void* __restrict__ C,
                    const float* __restrict__ bias,
                    const float* __restrict__ resid,
                    float scale, int K,
                    long long sA, long long sB, long long sC,
                    int ldc)
{
    // ---- XCD-bijective block swizzle (T1); all grids have nwg % 8 == 0.
    const unsigned nwg = gridDim.x * gridDim.y * gridDim.z;
    const unsigned bid = blockIdx.x + gridDim.x * (blockIdx.y + gridDim.y * blockIdx.z);
    const unsigned work = (bid & 7u) * (nwg >> 3) + (bid >> 3);
    const unsigned bx = work % gridDim.x;
    const unsigned rem = work / gridDim.x;
    const unsigned by = rem % gridDim.y;
    const unsigned bz = rem / gridDim.y;

    A += (long long)bz * sA;
    B += (long long)bz * sB;

    const int tid  = threadIdx.x;
    const int lane = tid & 63;
    const int w    = tid >> 6;
    const int wm   = w >> 2;      // 0..1
    const int wn   = w & 3;       // 0..3
    const int fr   = lane & 15;
    const int kg   = lane >> 4;
    const int swz  = (fr & 7) << 3;

    const int m0 = by * 256;
    const int n0 = bx * 256;

    __shared__ u16 lds[65536];    // 2 buffers x (A 256x64 + B 256x64)

    f32x4 acc[8][4] = {};
    bf16x8 a00[4], a10[4], a01[4], a11[4], b0[4], b1[4];

    const int sr  = tid >> 3;              // 0..63
    const int sc8 = (tid & 7) << 3;        // u16 chunk col
    const int scb = sc8 ^ ((sr & 7) << 3); // inverse-swizzled global col

    const int nk = K >> 6;

#define STAGE_A(tt, q01, bsel) { \
    const int kb_ = (tt) << 6; \
    u16* dst_ = &lds[(bsel) * 32768]; \
    { const int row_ = (q01) * 64 + sr; \
      gload16(A + (size_t)(m0 + row_) * K + kb_ + scb, &dst_[row_ * 64 + sc8]); } \
    { const int row_ = ((q01) + 2) * 64 + sr; \
      gload16(A + (size_t)(m0 + row_) * K + kb_ + scb, &dst_[row_ * 64 + sc8]); } }

#define STAGE_B(tt, h, bsel) { \
    const int kb_ = (tt) << 6; \
    u16* dst_ = &lds[(bsel) * 32768 + 16384]; \
    { const int row_ = (h) * 128 + sr; \
      gload16(B + (size_t)(n0 + row_) * K + kb_ + scb, &dst_[row_ * 64 + sc8]); } \
    { const int row_ = (h) * 128 + 64 + sr; \
      gload16(B + (size_t)(n0 + row_) * K + kb_ + scb, &dst_[row_ * 64 + sc8]); } }

#define READ_A(dst, mh, ks) { const int cb_ = (((ks) << 5) | (kg << 3)) ^ swz; \
    _Pragma("unroll") for (int i_ = 0; i_ < 4; ++i_) \
      dst[i_] = *(const bf16x8*)&Alp[(wm * 128 + (mh) * 64 + i_ * 16 + fr) * 64 + cb_]; }

#define READ_B(dst, ks) { const int cb_ = (((ks) << 5) | (kg << 3)) ^ swz; \
    _Pragma("unroll") for (int n_ = 0; n_ < 4; ++n_) \
      dst[n_] = *(const bf16x8*)&Blp[(wn * 64 + n_ * 16 + fr) * 64 + cb_]; }

#define MFMA_PH(mh, aset, bset) \
    _Pragma("unroll") for (int i_ = 0; i_ < 4; ++i_) \
      _Pragma("unroll") for (int n_ = 0; n_ < 4; ++n_) \
        acc[(mh)*4 + i_][n_] = __builtin_amdgcn_mfma_f32_16x16x32_bf16(aset[i_], bset[n_], acc[(mh)*4 + i_][n_], 0, 0, 0);

#define BAR()    __builtin_amdgcn_s_barrier()
#define SCHED0() __builtin_amdgcn_sched_barrier(0)
#define LGKM(n)  { asm volatile("s_waitcnt lgkmcnt(" #n ")" ::: "memory"); __builtin_amdgcn_sched_barrier(0); }
#define VM(n)    asm volatile("s_waitcnt vmcnt(" #n ")" ::: "memory")
#define PRIO1()  __builtin_amdgcn_s_setprio(1)
#define PRIO0()  __builtin_amdgcn_s_setprio(0)

    // prologue: tile 0, halves in issue order A0,B0,B1,A1
    STAGE_A(0, 0, 0); STAGE_B(0, 0, 0); STAGE_B(0, 1, 0); STAGE_A(0, 1, 0);
    VM(2); BAR();

    for (int t = 0; t < nk - 1; ++t) {
        const u16* Alp = &lds[(t & 1) * 32768];
        const u16* Blp = Alp + 16384;
        const int nb = (t + 1) & 1;
        // P1: reads for self (A1(t) may still be in flight -> can't pre-read it)
        READ_B(b0, 0); READ_A(a00, 0, 0); SCHED0();
        STAGE_A(t + 1, 0, nb); SCHED0();
        BAR(); LGKM(0);
        PRIO1(); MFMA_PH(0, a00, b0); PRIO0();
        VM(2); BAR();                       // A1(t) landed
        // P2: own reads (r2) + next phase's (r3); wait only r2
        READ_A(a10, 1, 0); SCHED0();
        READ_B(b1, 1); READ_A(a01, 0, 1); SCHED0();
        STAGE_B(t + 1, 0, nb); SCHED0();
        BAR(); LGKM(8);                     // r2 done, r3 (8) flying under MFMA
        PRIO1(); MFMA_PH(1, a10, b0); PRIO0();
        BAR();
        // P3: pre-issue P4's reads (r4); wait r3
        READ_A(a11, 1, 1); SCHED0();
        STAGE_B(t + 1, 1, nb); SCHED0();
        BAR(); LGKM(4);                     // r3 done, r4 (4) flying under MFMA
        PRIO1(); MFMA_PH(0, a01, b1); PRIO0();
        BAR();
        // P4: no reads; wait r4
        STAGE_A(t + 1, 1, nb); SCHED0();
        BAR(); LGKM(0);
        PRIO1(); MFMA_PH(1, a11, b1); PRIO0();
        VM(2); BAR();                       // A0,B0,B1(t+1) landed
    }
    {   // peeled last tile (no staging)
        const u16* Alp = &lds[((nk - 1) & 1) * 32768];
        const u16* Blp = Alp + 16384;
        READ_B(b0, 0); READ_A(a00, 0, 0); SCHED0();
        BAR(); LGKM(0);
        PRIO1(); MFMA_PH(0, a00, b0); PRIO0();
        VM(0); BAR();                       // A1(last) landed
        READ_A(a10, 1, 0); SCHED0();
        READ_B(b1, 1); READ_A(a01, 0, 1); SCHED0();
        BAR(); LGKM(8);
        PRIO1(); MFMA_PH(1, a10, b0); PRIO0();
        BAR();
        READ_A(a11, 1, 1); SCHED0();
        BAR(); LGKM(4);
        PRIO1(); MFMA_PH(0, a01, b1); PRIO0();
        BAR();
        BAR(); LGKM(0);
        PRIO1(); MFMA_PH(1, a11, b1); PRIO0();
        BAR();   // gates LDS reuse by epilogue
    }

    // ---- coalesced epilogues via per-wave LDS transpose ----
    const int cc = lane & 15;
    const int rg = lane >> 4;

    if constexpr (OUTMODE == 0 || OUTMODE == 2) {
        float* ep = (float*)lds + w * 1088;   // [16][68] f32 per wave
        const int rcol = cc * 4;              // readback col 0..63
        float4 b4 = make_float4(0.f, 0.f, 0.f, 0.f);
        if (bias) b4 = *(const float4*)&bias[n0 + wn * 64 + rcol];
#pragma unroll
        for (int m = 0; m < 8; ++m) {
#pragma unroll
            for (int n = 0; n < 4; ++n)
#pragma unroll
                for (int r = 0; r < 4; ++r)
                    ep[(rg * 4 + r) * 68 + n * 16 + cc] = acc[m][n][r];
            LGKM(0);
#pragma unroll
            for (int j = 0; j < 4; ++j) {
                const int row = j * 4 + rg;
                float4 v = *(const float4*)&ep[row * 68 + rcol];
                const int gr = m0 + wm * 128 + m * 16 + row;
                if constexpr (OUTMODE == 0) {
                    u16* Cb = (u16*)C + (long long)bz * sC;
                    ushort4 pk;
                    pk.x = f2b((v.x + b4.x) * scale);
                    pk.y = f2b((v.y + b4.y) * scale);
                    pk.z = f2b((v.z + b4.z) * scale);
                    pk.w = f2b((v.w + b4.w) * scale);
                    *(ushort4*)&Cb[(size_t)gr * ldc + n0 + wn * 64 + rcol] = pk;
                } else {
                    float* Cf = (float*)C;
                    size_t o = (size_t)gr * ldc + n0 + wn * 64 + rcol;
                    float4 rv = *(const float4*)&resid[o];
                    float4 ov;
                    ov.x = v.x + b4.x + rv.x;
                    ov.y = v.y + b4.y + rv.y;
                    ov.z = v.z + b4.z + rv.z;
                    ov.w = v.w + b4.w + rv.w;
                    *(float4*)&Cf[o] = ov;
                }
            }
            LGKM(0);
        }
    } else {
        // OUTMODE 1: vT[b][hcol][s] — full-LDS bf16 transpose, XOR-swizzled
        u16* epW = &lds[w * 8192];            // [64 cols][128 s] u16 per wave
        const int colb = n0 + wn * 64;
        float bv4[4];
#pragma unroll
        for (int n = 0; n < 4; ++n) bv4[n] = bias ? bias[colb + n * 16 + cc] : 0.f;
        const int swc = (cc & 7) << 3;
#pragma unroll
        for (int n = 0; n < 4; ++n) {
            const int col = n * 16 + cc;
#pragma unroll
            for (int m = 0; m < 8; ++m)
#pragma unroll
                for (int rp = 0; rp < 2; ++rp) {
                    const int s = m * 16 + rg * 4 + rp * 2;
                    unsigned lo = f2b((acc[m][n][rp * 2]     + bv4[n]) * scale);
                    unsigned hi = f2b((acc[m][n][rp * 2 + 1] + bv4[n]) * scale);
                    *(unsigned*)&epW[col * 128 + (s ^ swc)] = lo | (hi << 16);
                }
        }
        LGKM(0);
        const int b  = (m0 + wm * 128) >> 11;
        const int sb = (m0 + wm * 128) & 2047;
        u16* Vb = (u16*)C;
#pragma unroll
        for (int j = 0; j < 16; ++j) {
            const int col = j * 4 + rg;
            const int sc_ = (cc * 8) ^ ((col & 7) << 3);
            bf16x8 v = *(const bf16x8*)&epW[col * 128 + sc_];
            *(bf16x8*)&Vb[((size_t)b * HID + colb + col) * SEQ + sb + cc * 8] = v;
        }
    }
#undef STAGE_A
#undef STAGE_B
#undef READ_A
#undef READ_B
#undef MFMA_PH
#undef BAR
#undef SCHED0
#undef LGKM
#undef VM
#undef PRIO1
#undef PRIO0
}

// ---------- row softmax, in-place, bf16, row length 2048 ----------
__global__ __launch_bounds__(256)
void softmax_kernel(u16* __restrict__ sc) {
    const size_t row = blockIdx.x;
    u16* p = sc + row * 2048;
    const int tid = threadIdx.x;
    const int lane = tid & 63;
    const int w = tid >> 6;

    float v[8];
    ushort4 ua = *(const ushort4*)&p[tid * 8];
    ushort4 ub = *(const ushort4*)&p[tid * 8 + 4];
    v[0] = b2f(ua.x); v[1] = b2f(ua.y); v[2] = b2f(ua.z); v[3] = b2f(ua.w);
    v[4] = b2f(ub.x); v[5] = b2f(ub.y); v[6] = b2f(ub.z); v[7] = b2f(ub.w);

    float mx = v[0];
#pragma unroll
    for (int j = 1; j < 8; ++j) mx = fmaxf(mx, v[j]);
#pragma unroll
    for (int o = 32; o; o >>= 1) mx = fmaxf(mx, __shfl_xor(mx, o));

    __shared__ float red[8];
    if (!lane) red[w] = mx;
    __syncthreads();
    mx = fmaxf(fmaxf(red[0], red[1]), fmaxf(red[2], red[3]));

    float s = 0.f;
#pragma unroll
    for (int j = 0; j < 8; ++j) { v[j] = __expf(v[j] - mx); s += v[j]; }
#pragma unroll
    for (int o = 32; o; o >>= 1) s += __shfl_xor(s, o);
    if (!lane) red[4 + w] = s;
    __syncthreads();
    s = red[4] + red[5] + red[6] + red[7];
    float inv = 1.0f / s;

    ushort4 oa, ob;
    oa.x = f2b(v[0] * inv); oa.y = f2b(v[1] * inv); oa.z = f2b(v[2] * inv); oa.w = f2b(v[3] * inv);
    ob.x = f2b(v[4] * inv); ob.y = f2b(v[5] * inv); ob.z = f2b(v[6] * inv); ob.w = f2b(v[7] * inv);
    *(ushort4*)&p[tid * 8]     = oa;
    *(ushort4*)&p[tid * 8 + 4] = ob;
}

// ---------- in-place LayerNorm over rows of 1024 fp32 ----------
__global__ __launch_bounds__(256)
void layernorm_kernel(float* __restrict__ y,
                      const float* __restrict__ gamma,
                      const float* __restrict__ beta) {
    const size_t row = blockIdx.x;
    float* p = y + row * 1024;
    const int tid = threadIdx.x;
    const int lane = tid & 63;
    const int w = tid >> 6;

    float4 v = *(const float4*)&p[tid * 4];
    float s = v.x + v.y + v.z + v.w;
    float q = v.x * v.x + v.y * v.y + v.z * v.z + v.w * v.w;
#pragma unroll
    for (int o = 32; o; o >>= 1) { s += __shfl_xor(s, o); q += __shfl_xor(q, o); }

    __shared__ float red[16];
    if (!lane) { red[w] = s; red[8 + w] = q; }
    __syncthreads();
    s = red[0] + red[1] + red[2] + red[3];
    q = red[8] + red[9] + red[10] + red[11];

    const float mu  = s * (1.0f / 1024.0f);
    const float var = q * (1.0f / 1024.0f) - mu * mu;
    const float rs  = rsqrtf(var + 1e-5f);

    float4 g  = *(const float4*)&gamma[tid * 4];
    float4 be = *(const float4*)&beta[tid * 4];
    float4 o;
    o.x = (v.x - mu) * rs * g.x + be.x;
    o.y = (v.y - mu) * rs * g.y + be.y;
    o.z = (v.z - mu) * rs * g.z + be.z;
    o.w = (v.w - mu) * rs * g.w + be.w;
    *(float4*)&p[tid * 4] = o;
}

extern "C" void kernel_launch(void* const* d_in, const int* in_sizes, int n_in,
                              void* d_out, int out_size, void* d_ws, size_t ws_size,
                              hipStream_t stream) {
    const float* x     = (const float*)d_in[0];
    const float* Wq    = (const float*)d_in[1];
    const float* bq    = (const float*)d_in[2];
    const float* Wk    = (const float*)d_in[3];
    const float* bk    = (const float*)d_in[4];
    const float* Wv    = (const float*)d_in[5];
    const float* bv    = (const float*)d_in[6];
    const float* Wp    = (const float*)d_in[7];
    const float* bp    = (const float*)d_in[8];
    const float* gamma = (const float*)d_in[9];
    const float* beta  = (const float*)d_in[10];
    float* out = (float*)d_out;

    char* ws = (char*)d_ws;
    u16* xb     = (u16*)(ws + 0);
    u16* qb     = (u16*)(ws + 33554432);
    u16* kb     = (u16*)(ws + 67108864);
    u16* vT     = (u16*)(ws + 100663296);    // [8][1024][2048]
    u16* ctx    = (u16*)(ws + 134217728);
    u16* wqb    = (u16*)(ws + 167772160);
    u16* wkb    = (u16*)(ws + 169869312);
    u16* wvb    = (u16*)(ws + 171966464);
    u16* wpb    = (u16*)(ws + 174063616);
    u16* scores = (u16*)(ws + 176160768);

    cvt_kernel<<<16384, 256, 0, stream>>>(x,  xb,  NROWS * HID);
    cvt_kernel<<<1024, 256, 0, stream>>>(Wq, wqb, HID * HID);
    cvt_kernel<<<1024, 256, 0, stream>>>(Wk, wkb, HID * HID);
    cvt_kernel<<<1024, 256, 0, stream>>>(Wv, wvb, HID * HID);
    cvt_kernel<<<1024, 256, 0, stream>>>(Wp, wpb, HID * HID);

    dim3 blk(512);
    // q/k/v projections  (q folded with 1/sqrt(H)=1/32)
    gemm_bt_kernel<0><<<dim3(4, 64, 1), blk, 0, stream>>>(xb, wqb, qb, bq, nullptr, 0.03125f, HID, 0, 0, 0, HID);
    gemm_bt_kernel<0><<<dim3(4, 64, 1), blk, 0, stream>>>(xb, wkb, kb, bk, nullptr, 1.0f,     HID, 0, 0, 0, HID);
    gemm_bt_kernel<1><<<dim3(4, 64, 1), blk, 0, stream>>>(xb, wvb, vT, bv, nullptr, 1.0f,     HID, 0, 0, 0, 0);

    // scores = q' @ k^T  (per batch)
    gemm_bt_kernel<0><<<dim3(8, 8, 8), blk, 0, stream>>>(
        qb, kb, scores, nullptr, nullptr, 1.0f, HID,
        (long long)SEQ * HID, (long long)SEQ * HID, (long long)SEQ * SEQ, SEQ);

    softmax_kernel<<<NROWS, 256, 0, stream>>>(scores);

    // context = attn @ v  (B = vT, K-contiguous)
    gemm_bt_kernel<0><<<dim3(4, 8, 8), blk, 0, stream>>>(
        scores, vT, ctx, nullptr, nullptr, 1.0f, SEQ,
        (long long)SEQ * SEQ, (long long)HID * SEQ, (long long)SEQ * HID, HID);

    // out = ctx @ Wp^T + bp + x  (fp32 into d_out)
    gemm_bt_kernel<2><<<dim3(4, 64, 1), blk, 0, stream>>>(ctx, wpb, out, bp, x, 1.0f, HID, 0, 0, 0, HID);

    layernorm_kernel<<<NROWS, 256, 0, stream>>>(out, gamma, beta);
}

// Round 7
// 366.464 us; speedup vs baseline: 1.0773x; 1.0103x over previous
//
#include <hip/hip_runtime.h>
#include <hip/hip_bf16.h>

typedef __attribute__((ext_vector_type(4))) float f32x4;
typedef __attribute__((ext_vector_type(8))) short bf16x8;
typedef unsigned short u16;

#define SEQ 2048
#define HID 1024
#define NROWS 16384

// ---------- helpers ----------
__device__ __forceinline__ float b2f(u16 u) {
    union { float f; unsigned i; } x; x.i = ((unsigned)u) << 16; return x.f;
}
__device__ __forceinline__ u16 f2b(float f) {
    unsigned x = __float_as_uint(f);
    return (u16)((x + 0x7fffu + ((x >> 16) & 1u)) >> 16);
}
__device__ __forceinline__ void gload16(const u16* g, u16* l) {
    __builtin_amdgcn_global_load_lds(
        (const __attribute__((address_space(1))) void*)g,
        (__attribute__((address_space(3))) void*)l,
        16, 0, 0);
}

// ---------- fp32 -> bf16 convert ----------
__global__ __launch_bounds__(256)
void cvt_kernel(const float* __restrict__ src, u16* __restrict__ dst, int n) {
    int base = (blockIdx.x * 256 + threadIdx.x) * 4;
    if (base < n) {
        float4 v = *(const float4*)&src[base];
        ushort4 o;
        o.x = f2b(v.x); o.y = f2b(v.y); o.z = f2b(v.z); o.w = f2b(v.w);
        *(ushort4*)&dst[base] = o;
    }
}

// ---------- GEMM: C = A @ B^T (+bias)*scale (+resid) ----------
// 256x256 tile, BK=64, 512 thr (8 waves 2Mx4N), per-wave 128x64 out,
// 16x16x32 MFMA, conflict-free XOR-swizzled LDS (T2, rule 21).
// R7 structure: ONE s_barrier + ONE vmcnt(0) per K-tile; full-tile prefetch
// (8 gload_lds) issued immediately after the barrier (issue-to-wait distance
// = one full tile of compute ~2400cyc); NO intra-tile barriers -> compiler
// freely interleaves the tile's 24 ds_read_b128 with its 64 MFMAs (the
// serialization that capped R4/R6 at 37% MfmaUtil).
// Race-freedom: a wave's reads of tile t-1 are lgkm-consumed by its MFMAs
// before it reaches tile t's barrier; STAGE(t+1) into that buffer is issued
// only after the barrier.
template<int OUTMODE>
__global__ __launch_bounds__(512, 2)
void gemm_bt_kernel(const u16* __restrict__ A, const u16* __restrict__ B,
                    void* __restrict__ C,
                    const float* __restrict__ bias,
                    const float* __restrict__ resid,
                    float scale, int K,
                    long long sA, long long sB, long long sC,
                    int ldc)
{
    // ---- XCD-bijective block swizzle (T1); all grids have nwg % 8 == 0.
    const unsigned nwg = gridDim.x * gridDim.y * gridDim.z;
    const unsigned bid = blockIdx.x + gridDim.x * (blockIdx.y + gridDim.y * blockIdx.z);
    const unsigned work = (bid & 7u) * (nwg >> 3) + (bid >> 3);
    const unsigned bx = work % gridDim.x;
    const unsigned rem = work / gridDim.x;
    const unsigned by = rem % gridDim.y;
    const unsigned bz = rem / gridDim.y;

    A += (long long)bz * sA;
    B += (long long)bz * sB;

    const int tid  = threadIdx.x;
    const int lane = tid & 63;
    const int w    = tid >> 6;
    const int wm   = w >> 2;      // 0..1
    const int wn   = w & 3;       // 0..3
    const int fr   = lane & 15;
    const int kg   = lane >> 4;
    const int swz  = (fr & 7) << 3;

    const int m0 = by * 256;
    const int n0 = bx * 256;

    __shared__ u16 lds[65536];    // 2 buffers x (A 256x64 + B 256x64)

    f32x4 acc[8][4] = {};
    bf16x8 a00[4], a10[4], a01[4], a11[4], b0[4], b1[4];

    const int sr  = tid >> 3;              // 0..63
    const int sc8 = (tid & 7) << 3;        // u16 chunk col
    const int scb = sc8 ^ ((sr & 7) << 3); // inverse-swizzled global col

    const int nk = K >> 6;

#define STAGE_A(tt, q01, bsel) { \
    const int kb_ = (tt) << 6; \
    u16* dst_ = &lds[(bsel) * 32768]; \
    { const int row_ = (q01) * 64 + sr; \
      gload16(A + (size_t)(m0 + row_) * K + kb_ + scb, &dst_[row_ * 64 + sc8]); } \
    { const int row_ = ((q01) + 2) * 64 + sr; \
      gload16(A + (size_t)(m0 + row_) * K + kb_ + scb, &dst_[row_ * 64 + sc8]); } }

#define STAGE_B(tt, h, bsel) { \
    const int kb_ = (tt) << 6; \
    u16* dst_ = &lds[(bsel) * 32768 + 16384]; \
    { const int row_ = (h) * 128 + sr; \
      gload16(B + (size_t)(n0 + row_) * K + kb_ + scb, &dst_[row_ * 64 + sc8]); } \
    { const int row_ = (h) * 128 + 64 + sr; \
      gload16(B + (size_t)(n0 + row_) * K + kb_ + scb, &dst_[row_ * 64 + sc8]); } }

#define READ_A(dst, mh, ks) { const int cb_ = (((ks) << 5) | (kg << 3)) ^ swz; \
    _Pragma("unroll") for (int i_ = 0; i_ < 4; ++i_) \
      dst[i_] = *(const bf16x8*)&Alp[(wm * 128 + (mh) * 64 + i_ * 16 + fr) * 64 + cb_]; }

#define READ_B(dst, ks) { const int cb_ = (((ks) << 5) | (kg << 3)) ^ swz; \
    _Pragma("unroll") for (int n_ = 0; n_ < 4; ++n_) \
      dst[n_] = *(const bf16x8*)&Blp[(wn * 64 + n_ * 16 + fr) * 64 + cb_]; }

#define MFMA_PH(mh, aset, bset) \
    _Pragma("unroll") for (int i_ = 0; i_ < 4; ++i_) \
      _Pragma("unroll") for (int n_ = 0; n_ < 4; ++n_) \
        acc[(mh)*4 + i_][n_] = __builtin_amdgcn_mfma_f32_16x16x32_bf16(aset[i_], bset[n_], acc[(mh)*4 + i_][n_], 0, 0, 0);

#define BAR()    __builtin_amdgcn_s_barrier()
#define SCHED0() __builtin_amdgcn_sched_barrier(0)
#define LGKM0()  { asm volatile("s_waitcnt lgkmcnt(0)" ::: "memory"); __builtin_amdgcn_sched_barrier(0); }
#define VM0()    asm volatile("s_waitcnt vmcnt(0)" ::: "memory")

    // prologue: stage tile 0 into buf 0
    STAGE_A(0, 0, 0); STAGE_B(0, 0, 0); STAGE_B(0, 1, 0); STAGE_A(0, 1, 0);

    for (int t = 0; t < nk; ++t) {
        VM0();          // tile t landed (issued one full tile ago, except t=0)
        BAR();          // visible to all; all waves done reading buf nb's old tile
        SCHED0();
        if (t + 1 < nk) {
            const int nb = (t + 1) & 1;
            STAGE_A(t + 1, 0, nb); STAGE_B(t + 1, 0, nb);
            STAGE_B(t + 1, 1, nb); STAGE_A(t + 1, 1, nb);
            SCHED0();
        }
        const u16* Alp = &lds[(t & 1) * 32768];
        const u16* Blp = Alp + 16384;
        // whole-tile reads + MFMAs; compiler schedules the interleave
        READ_B(b0, 0); READ_A(a00, 0, 0);
        MFMA_PH(0, a00, b0);
        READ_A(a10, 1, 0);
        MFMA_PH(1, a10, b0);
        READ_B(b1, 1); READ_A(a01, 0, 1);
        MFMA_PH(0, a01, b1);
        READ_A(a11, 1, 1);
        MFMA_PH(1, a11, b1);
    }
    BAR();   // gates LDS reuse by epilogue

    // ---- coalesced epilogues via per-wave LDS transpose ----
    const int cc = lane & 15;
    const int rg = lane >> 4;

    if constexpr (OUTMODE == 0 || OUTMODE == 2) {
        float* ep = (float*)lds + w * 1088;   // [16][68] f32 per wave
        const int rcol = cc * 4;              // readback col 0..63
        float4 b4 = make_float4(0.f, 0.f, 0.f, 0.f);
        if (bias) b4 = *(const float4*)&bias[n0 + wn * 64 + rcol];
#pragma unroll
        for (int m = 0; m < 8; ++m) {
#pragma unroll
            for (int n = 0; n < 4; ++n)
#pragma unroll
                for (int r = 0; r < 4; ++r)
                    ep[(rg * 4 + r) * 68 + n * 16 + cc] = acc[m][n][r];
            LGKM0();
#pragma unroll
            for (int j = 0; j < 4; ++j) {
                const int row = j * 4 + rg;
                float4 v = *(const float4*)&ep[row * 68 + rcol];
                const int gr = m0 + wm * 128 + m * 16 + row;
                if constexpr (OUTMODE == 0) {
                    u16* Cb = (u16*)C + (long long)bz * sC;
                    ushort4 pk;
                    pk.x = f2b((v.x + b4.x) * scale);
                    pk.y = f2b((v.y + b4.y) * scale);
                    pk.z = f2b((v.z + b4.z) * scale);
                    pk.w = f2b((v.w + b4.w) * scale);
                    *(ushort4*)&Cb[(size_t)gr * ldc + n0 + wn * 64 + rcol] = pk;
                } else {
                    float* Cf = (float*)C;
                    size_t o = (size_t)gr * ldc + n0 + wn * 64 + rcol;
                    float4 rv = *(const float4*)&resid[o];
                    float4 ov;
                    ov.x = v.x + b4.x + rv.x;
                    ov.y = v.y + b4.y + rv.y;
                    ov.z = v.z + b4.z + rv.z;
                    ov.w = v.w + b4.w + rv.w;
                    *(float4*)&Cf[o] = ov;
                }
            }
            LGKM0();
        }
    } else {
        // OUTMODE 1: vT[b][hcol][s] — full-LDS bf16 transpose, XOR-swizzled
        u16* epW = &lds[w * 8192];            // [64 cols][128 s] u16 per wave
        const int colb = n0 + wn * 64;
        float bv4[4];
#pragma unroll
        for (int n = 0; n < 4; ++n) bv4[n] = bias ? bias[colb + n * 16 + cc] : 0.f;
        const int swc = (cc & 7) << 3;
#pragma unroll
        for (int n = 0; n < 4; ++n) {
            const int col = n * 16 + cc;
#pragma unroll
            for (int m = 0; m < 8; ++m)
#pragma unroll
                for (int rp = 0; rp < 2; ++rp) {
                    const int s = m * 16 + rg * 4 + rp * 2;
                    unsigned lo = f2b((acc[m][n][rp * 2]     + bv4[n]) * scale);
                    unsigned hi = f2b((acc[m][n][rp * 2 + 1] + bv4[n]) * scale);
                    *(unsigned*)&epW[col * 128 + (s ^ swc)] = lo | (hi << 16);
                }
        }
        LGKM0();
        const int b  = (m0 + wm * 128) >> 11;
        const int sb = (m0 + wm * 128) & 2047;
        u16* Vb = (u16*)C;
#pragma unroll
        for (int j = 0; j < 16; ++j) {
            const int col = j * 4 + rg;
            const int sc_ = (cc * 8) ^ ((col & 7) << 3);
            bf16x8 v = *(const bf16x8*)&epW[col * 128 + sc_];
            *(bf16x8*)&Vb[((size_t)b * HID + colb + col) * SEQ + sb + cc * 8] = v;
        }
    }
#undef STAGE_A
#undef STAGE_B
#undef READ_A
#undef READ_B
#undef MFMA_PH
#undef BAR
#undef SCHED0
#undef LGKM0
#undef VM0
}

// ---------- row softmax, in-place, bf16, row length 2048 ----------
__global__ __launch_bounds__(256)
void softmax_kernel(u16* __restrict__ sc) {
    const size_t row = blockIdx.x;
    u16* p = sc + row * 2048;
    const int tid = threadIdx.x;
    const int lane = tid & 63;
    const int w = tid >> 6;

    float v[8];
    ushort4 ua = *(const ushort4*)&p[tid * 8];
    ushort4 ub = *(const ushort4*)&p[tid * 8 + 4];
    v[0] = b2f(ua.x); v[1] = b2f(ua.y); v[2] = b2f(ua.z); v[3] = b2f(ua.w);
    v[4] = b2f(ub.x); v[5] = b2f(ub.y); v[6] = b2f(ub.z); v[7] = b2f(ub.w);

    float mx = v[0];
#pragma unroll
    for (int j = 1; j < 8; ++j) mx = fmaxf(mx, v[j]);
#pragma unroll
    for (int o = 32; o; o >>= 1) mx = fmaxf(mx, __shfl_xor(mx, o));

    __shared__ float red[8];
    if (!lane) red[w] = mx;
    __syncthreads();
    mx = fmaxf(fmaxf(red[0], red[1]), fmaxf(red[2], red[3]));

    float s = 0.f;
#pragma unroll
    for (int j = 0; j < 8; ++j) { v[j] = __expf(v[j] - mx); s += v[j]; }
#pragma unroll
    for (int o = 32; o; o >>= 1) s += __shfl_xor(s, o);
    if (!lane) red[4 + w] = s;
    __syncthreads();
    s = red[4] + red[5] + red[6] + red[7];
    float inv = 1.0f / s;

    ushort4 oa, ob;
    oa.x = f2b(v[0] * inv); oa.y = f2b(v[1] * inv); oa.z = f2b(v[2] * inv); oa.w = f2b(v[3] * inv);
    ob.x = f2b(v[4] * inv); ob.y = f2b(v[5] * inv); ob.z = f2b(v[6] * inv); ob.w = f2b(v[7] * inv);
    *(ushort4*)&p[tid * 8]     = oa;
    *(ushort4*)&p[tid * 8 + 4] = ob;
}

// ---------- in-place LayerNorm over rows of 1024 fp32 ----------
__global__ __launch_bounds__(256)
void layernorm_kernel(float* __restrict__ y,
                      const float* __restrict__ gamma,
                      const float* __restrict__ beta) {
    const size_t row = blockIdx.x;
    float* p = y + row * 1024;
    const int tid = threadIdx.x;
    const int lane = tid & 63;
    const int w = tid >> 6;

    float4 v = *(const float4*)&p[tid * 4];
    float s = v.x + v.y + v.z + v.w;
    float q = v.x * v.x + v.y * v.y + v.z * v.z + v.w * v.w;
#pragma unroll
    for (int o = 32; o; o >>= 1) { s += __shfl_xor(s, o); q += __shfl_xor(q, o); }

    __shared__ float red[16];
    if (!lane) { red[w] = s; red[8 + w] = q; }
    __syncthreads();
    s = red[0] + red[1] + red[2] + red[3];
    q = red[8] + red[9] + red[10] + red[11];

    const float mu  = s * (1.0f / 1024.0f);
    const float var = q * (1.0f / 1024.0f) - mu * mu;
    const float rs  = rsqrtf(var + 1e-5f);

    float4 g  = *(const float4*)&gamma[tid * 4];
    float4 be = *(const float4*)&beta[tid * 4];
    float4 o;
    o.x = (v.x - mu) * rs * g.x + be.x;
    o.y = (v.y - mu) * rs * g.y + be.y;
    o.z = (v.z - mu) * rs * g.z + be.z;
    o.w = (v.w - mu) * rs * g.w + be.w;
    *(float4*)&p[tid * 4] = o;
}

extern "C" void kernel_launch(void* const* d_in, const int* in_sizes, int n_in,
                              void* d_out, int out_size, void* d_ws, size_t ws_size,
                              hipStream_t stream) {
    const float* x     = (const float*)d_in[0];
    const float* Wq    = (const float*)d_in[1];
    const float* bq    = (const float*)d_in[2];
    const float* Wk    = (const float*)d_in[3];
    const float* bk    = (const float*)d_in[4];
    const float* Wv    = (const float*)d_in[5];
    const float* bv    = (const float*)d_in[6];
    const float* Wp    = (const float*)d_in[7];
    const float* bp    = (const float*)d_in[8];
    const float* gamma = (const float*)d_in[9];
    const float* beta  = (const float*)d_in[10];
    float* out = (float*)d_out;

    char* ws = (char*)d_ws;
    u16* xb     = (u16*)(ws + 0);
    u16* qb     = (u16*)(ws + 33554432);
    u16* kb     = (u16*)(ws + 67108864);
    u16* vT     = (u16*)(ws + 100663296);    // [8][1024][2048]
    u16* ctx    = (u16*)(ws + 134217728);
    u16* wqb    = (u16*)(ws + 167772160);
    u16* wkb    = (u16*)(ws + 169869312);
    u16* wvb    = (u16*)(ws + 171966464);
    u16* wpb    = (u16*)(ws + 174063616);
    u16* scores = (u16*)(ws + 176160768);

    cvt_kernel<<<16384, 256, 0, stream>>>(x,  xb,  NROWS * HID);
    cvt_kernel<<<1024, 256, 0, stream>>>(Wq, wqb, HID * HID);
    cvt_kernel<<<1024, 256, 0, stream>>>(Wk, wkb, HID * HID);
    cvt_kernel<<<1024, 256, 0, stream>>>(Wv, wvb, HID * HID);
    cvt_kernel<<<1024, 256, 0, stream>>>(Wp, wpb, HID * HID);

    dim3 blk(512);
    // q/k/v projections  (q folded with 1/sqrt(H)=1/32)
    gemm_bt_kernel<0><<<dim3(4, 64, 1), blk, 0, stream>>>(xb, wqb, qb, bq, nullptr, 0.03125f, HID, 0, 0, 0, HID);
    gemm_bt_kernel<0><<<dim3(4, 64, 1), blk, 0, stream>>>(xb, wkb, kb, bk, nullptr, 1.0f,     HID, 0, 0, 0, HID);
    gemm_bt_kernel<1><<<dim3(4, 64, 1), blk, 0, stream>>>(xb, wvb, vT, bv, nullptr, 1.0f,     HID, 0, 0, 0, 0);

    // scores = q' @ k^T  (per batch)
    gemm_bt_kernel<0><<<dim3(8, 8, 8), blk, 0, stream>>>(
        qb, kb, scores, nullptr, nullptr, 1.0f, HID,
        (long long)SEQ * HID, (long long)SEQ * HID, (long long)SEQ * SEQ, SEQ);

    softmax_kernel<<<NROWS, 256, 0, stream>>>(scores);

    // context = attn @ v  (B = vT, K-contiguous)
    gemm_bt_kernel<0><<<dim3(4, 8, 8), blk, 0, stream>>>(
        scores, vT, ctx, nullptr, nullptr, 1.0f, SEQ,
        (long long)SEQ * SEQ, (long long)HID * SEQ, (long long)SEQ * HID, HID);

    // out = ctx @ Wp^T + bp + x  (fp32 into d_out)
    gemm_bt_kernel<2><<<dim3(4, 64, 1), blk, 0, stream>>>(ctx, wpb, out, bp, x, 1.0f, HID, 0, 0, 0, HID);

    layernorm_kernel<<<NROWS, 256, 0, stream>>>(out, gamma, beta);
}